// Round 6
// baseline (418.590 us; speedup 1.0000x reference)
//
#include <hip/hip_runtime.h>

constexpr int BN = 4;       // batches
constexpr int NV = 25600;   // vertices (160*160)
constexpr int DD = 64;      // D
constexpr int PP = 72;      // ns: bf16 LDS row pitch (16B-aligned rows)
constexpr int KP = 34;      // node: halfword pitch -> dword stride 17
constexpr int NS_ITERS = 15;

typedef __attribute__((ext_vector_type(8))) short short8;
typedef __attribute__((ext_vector_type(4))) float floatx4;

__device__ __forceinline__ unsigned short f2bf(float x) {
    unsigned u = __float_as_uint(x);
    u += 0x7fffu + ((u >> 16) & 1u);        // round-to-nearest-even
    return (unsigned short)(u >> 16);
}
__device__ __forceinline__ float bf2f(unsigned short h) {
    return __uint_as_float(((unsigned)h) << 16);
}

// rowptr + zero M + zero out (fused: fewer dispatches)
__global__ void rowptr_kernel(const int* __restrict__ e0, int E, int* __restrict__ row_ptr,
                              float* __restrict__ M, float* __restrict__ out) {
    int i = blockIdx.x * blockDim.x + threadIdx.x;
    if (i < BN * 64 * 64) M[i] = 0.f;
    if (i == 0) out[0] = 0.f;
    if (i > NV) return;
    int lo = 0, hi = E;
    while (lo < hi) {
        int mid = (lo + hi) >> 1;
        if (e0[mid] < i) lo = mid + 1; else hi = mid;
    }
    row_ptr[i] = lo;
}

// load an MFMA A/B fragment (8 consecutive halfwords) from a [64][KP] panel
__device__ __forceinline__ short8 ldfrag(const unsigned short* a, int row, int quad) {
    const unsigned* p = (const unsigned*)(a + row * KP + quad * 8);  // even offset -> uint-aligned
    union { unsigned u[4]; short8 s; } t;
    t.u[0] = p[0]; t.u[1] = p[1]; t.u[2] = p[2]; t.u[3] = p[3];
    return t.s;
}

// One wave per node (lane = d column). 4 nodes per block per chunk.
// Phase 2 is an MFMA rank-32 (24 used + 8 zero-pad) update with bf16 hi/lo
// split (3 MFMAs: hh, hl, lh), fp32 accumulation in VGPRs across chunks.
// 8 blocks/CU for latency hiding of the neighbor-gather.
__global__ __launch_bounds__(256, 8) void node_kernel(
    const float* __restrict__ x, const float* __restrict__ J,
    const int* __restrict__ e1, const int* __restrict__ row_ptr,
    float* __restrict__ M)
{
    const int b    = blockIdx.y;
    const int w    = __builtin_amdgcn_readfirstlane(threadIdx.x >> 6);  // uniform wave id
    const int lane = threadIdx.x & 63;   // d index in phase 1
    const int quad = lane >> 4;
    const int mrow = lane & 15;
    const int r0   = w * 16;             // this wave's output row strip

    // A^T, B^T panels: [d/e][k], k=0..23 written each chunk, 24..31 stay zero
    __shared__ unsigned short ATh[64 * KP], ATl[64 * KP];
    __shared__ unsigned short BTh[64 * KP], BTl[64 * KP];

    for (int i = threadIdx.x; i < 64 * KP; i += 256) {
        ATh[i] = 0; ATl[i] = 0; BTh[i] = 0; BTl[i] = 0;
    }
    __syncthreads();

    const floatx4 zero4 = {0.f, 0.f, 0.f, 0.f};
    floatx4 accM[4];
#pragma unroll
    for (int c = 0; c < 4; c++) accM[c] = zero4;

    const float* xb = x + (size_t)b * NV * 3;
    const float* Jb = J + (size_t)b * 3 * NV * DD;

    for (int chunk = blockIdx.x; chunk < NV / 4; chunk += gridDim.x) {
        const int n   = chunk * 4 + w;
        const int beg = row_ptr[n];
        const int deg = row_ptr[n + 1] - beg;

        // neighbor indices (scalar loads; padded with self -> zero contribution)
        int mm[6];
#pragma unroll
        for (int k = 0; k < 6; k++) {
            const int idx = beg + ((k < deg) ? k : 0);
            const int mv  = e1[idx];
            mm[k] = (k < deg) ? mv : n;
        }

        // issue ALL global loads up front (one latency window)
        const float* Jn = Jb + n * 3 * DD + lane;
        const float jn0 = Jn[0], jn1 = Jn[DD], jn2 = Jn[2 * DD];
        float jm0[6], jm1[6], jm2[6];
#pragma unroll
        for (int k = 0; k < 6; k++) {
            const float* Jm = Jb + mm[k] * 3 * DD + lane;
            jm0[k] = Jm[0]; jm1[k] = Jm[DD]; jm2[k] = Jm[2 * DD];
        }
        const float xn0 = xb[n * 3 + 0], xn1 = xb[n * 3 + 1], xn2 = xb[n * 3 + 2];
        float va0[6], va1[6], va2[6];
#pragma unroll
        for (int k = 0; k < 6; k++) {
            va0[k] = xn0 - xb[mm[k] * 3 + 0];
            va1[k] = xn1 - xb[mm[k] * 3 + 1];
            va2[k] = xn2 - xb[mm[k] * 3 + 2];
        }

        float lj0 = 0, lj1 = 0, lj2 = 0, bt0 = 0, bt1 = 0, bt2 = 0;
        float cxx = 0, cxy = 0, cxz = 0, cyy = 0, cyz = 0, czz = 0;
#pragma unroll
        for (int k = 0; k < 6; k++) {
            const float v0 = va0[k], v1 = va1[k], v2 = va2[k];
            const float t0 = jm0[k] - jn0, t1 = jm1[k] - jn1, t2 = jm2[k] - jn2;
            lj0 -= t0; lj1 -= t1; lj2 -= t2;
            bt0 += v1 * t2 - v2 * t1;
            bt1 += v2 * t0 - v0 * t2;
            bt2 += v0 * t1 - v1 * t0;
            const float s2 = v0 * v0 + v1 * v1 + v2 * v2;
            cxx += s2 - v0 * v0; cyy += s2 - v1 * v1; czz += s2 - v2 * v2;
            cxy -= v0 * v1; cxz -= v0 * v2; cyz -= v1 * v2;
        }
        // safety tail (never taken on this mesh: max degree 6)
        for (int e = beg + 6; e < beg + deg; e++) {
            const int m = e1[e];
            const float v0 = xn0 - xb[m * 3 + 0];
            const float v1 = xn1 - xb[m * 3 + 1];
            const float v2 = xn2 - xb[m * 3 + 2];
            const float* Jm = Jb + m * 3 * DD + lane;
            const float t0 = Jm[0] - jn0, t1 = Jm[DD] - jn1, t2 = Jm[2 * DD] - jn2;
            lj0 -= t0; lj1 -= t1; lj2 -= t2;
            bt0 += v1 * t2 - v2 * t1;
            bt1 += v2 * t0 - v0 * t2;
            bt2 += v0 * t1 - v1 * t0;
            const float s2 = v0 * v0 + v1 * v1 + v2 * v2;
            cxx += s2 - v0 * v0; cyy += s2 - v1 * v1; czz += s2 - v2 * v2;
            cxy -= v0 * v1; cxz -= v0 * v2; cyz -= v1 * v2;
        }

        lj0 *= 2.f; lj1 *= 2.f; lj2 *= 2.f;
        const float co00 = cyy * czz - cyz * cyz;
        const float co01 = cxz * cyz - cxy * czz;
        const float co02 = cxy * cyz - cxz * cyy;
        const float det  = cxx * co00 + cxy * co01 + cxz * co02;
        const float id   = 1.0f / det;
        const float i00 = co00 * id, i01 = co01 * id, i02 = co02 * id;
        const float i11 = (cxx * czz - cxz * cxz) * id;
        const float i12 = (cxz * cxy - cxx * cyz) * id;
        const float i22 = (cxx * cyy - cxy * cxy) * id;
        const float cb0 = i00 * bt0 + i01 * bt1 + i02 * bt2;
        const float cb1 = i01 * bt0 + i11 * bt1 + i12 * bt2;
        const float cb2 = i02 * bt0 + i12 * bt1 + i22 * bt2;

        // transposed bf16 hi/lo writeback: row d=lane, k = w*6 + i
        {
            const int kA = w * 6;
            float av[6] = {jn0, jn1, jn2, bt0, bt1, bt2};
            float bv[6] = {lj0, lj1, lj2, -cb0, -cb1, -cb2};
#pragma unroll
            for (int i = 0; i < 6; i++) {
                unsigned short h = f2bf(av[i]);
                ATh[lane * KP + kA + i] = h;
                ATl[lane * KP + kA + i] = f2bf(av[i] - bf2f(h));
                h = f2bf(bv[i]);
                BTh[lane * KP + kA + i] = h;
                BTl[lane * KP + kA + i] = f2bf(bv[i] - bf2f(h));
            }
        }
        __syncthreads();

        // phase 2: 16x16x32 MFMA over K=32 (24 used), 4 col-tiles per wave
        const short8 ah = ldfrag(ATh, r0 + mrow, quad);
        const short8 al = ldfrag(ATl, r0 + mrow, quad);
#pragma unroll
        for (int c = 0; c < 4; c++) {
            const short8 bh = ldfrag(BTh, c * 16 + mrow, quad);
            const short8 bl = ldfrag(BTl, c * 16 + mrow, quad);
            accM[c] = __builtin_amdgcn_mfma_f32_16x16x32_bf16(ah, bh, accM[c], 0, 0, 0);
            accM[c] = __builtin_amdgcn_mfma_f32_16x16x32_bf16(ah, bl, accM[c], 0, 0, 0);
            accM[c] = __builtin_amdgcn_mfma_f32_16x16x32_bf16(al, bh, accM[c], 0, 0, 0);
        }
        __syncthreads();
    }

    float* Mb = M + b * 4096;
#pragma unroll
    for (int c = 0; c < 4; c++)
#pragma unroll
        for (int r = 0; r < 4; r++)
            atomicAdd(&Mb[(r0 + quad * 4 + r) * 64 + (c * 16 + mrow)], accM[c][r]);
}

// ---------------------------------------------------------------------------
// trace(sqrtm(M + delta*I)) via coupled Newton-Schulz, bf16-split MFMA matmuls.
// 4 waves (16-row strip each), double-buffered Y/Z -> only 2 barriers/iter:
//   P1: T=Z*Y (regs); WB W=1.5I-0.5T (no barrier needed: W has no readers yet)
//   sync1; P2: Y'=Y*W, Z'=W*Z -> write to ALTERNATE buffers (no anti-dep);
//   sync2.
// ---------------------------------------------------------------------------
__global__ __launch_bounds__(256) void ns_sqrt_kernel(const float* __restrict__ M,
                                                      float* __restrict__ out)
{
    const int b    = blockIdx.x;
    const int tid  = threadIdx.x;
    const int w    = tid >> 6;
    const int lane = tid & 63;
    const int quad = lane >> 4;
    const int mrow = lane & 15;
    const int r0   = w * 16;             // this wave's output row strip

    __shared__ __align__(16) unsigned short Yh[2][64 * PP], Yl[2][64 * PP];
    __shared__ __align__(16) unsigned short Zh[2][64 * PP], Zl[2][64 * PP];
    __shared__ __align__(16) unsigned short Wh[64 * PP], Wl[64 * PP];
    __shared__ float tr_s;

    const float* Mb = M + b * 4096;

    // trace of M (one wave)
    if (tid < 64) {
        float d = Mb[tid * 64 + tid];
#pragma unroll
        for (int off = 32; off; off >>= 1) d += __shfl_down(d, off, 64);
        if (tid == 0) tr_s = d;
    }
    __syncthreads();
    const float tr    = tr_s;
    const float delta = 3e-5f * tr;
    const float cnorm = tr + 64.f * delta;   // >= lambda_max of shifted matrix
    const float inv_c = 1.f / cnorm;

    // Y0 = (M + delta I)/c  (bf16 hi/lo split), Z0 = I  -> buffer 0
    for (int i = tid; i < 4096; i += 256) {
        const int r = i >> 6, col = i & 63;
        float v = Mb[i] * inv_c;
        if (r == col) v += delta * inv_c;
        const unsigned short h = f2bf(v);
        Yh[0][r * PP + col] = h;
        Yl[0][r * PP + col] = f2bf(v - bf2f(h));
        Zh[0][r * PP + col] = (r == col) ? (unsigned short)0x3f80 : (unsigned short)0;
        Zl[0][r * PP + col] = 0;
    }
    __syncthreads();

    const floatx4 zero4 = {0.f, 0.f, 0.f, 0.f};

    for (int it = 0; it < NS_ITERS; ++it) {
        const int cur = it & 1, nxt = cur ^ 1;
        const unsigned short* yh = Yh[cur]; const unsigned short* yl = Yl[cur];
        const unsigned short* zh = Zh[cur]; const unsigned short* zl = Zl[cur];

        // ---- phase 1: T = Z*Y ----
        floatx4 accT[4];
#pragma unroll
        for (int c = 0; c < 4; c++) accT[c] = zero4;
#pragma unroll
        for (int ks = 0; ks < 2; ks++) {
            const int ko = ks * 32 + quad * 8;
            const short8 zah = *(const short8*)&zh[(r0 + mrow) * PP + ko];
            const short8 zal = *(const short8*)&zl[(r0 + mrow) * PP + ko];
#pragma unroll
            for (int c = 0; c < 4; c++) {
                const short8 ybh = *(const short8*)&yh[(c * 16 + mrow) * PP + ko];
                const short8 ybl = *(const short8*)&yl[(c * 16 + mrow) * PP + ko];
                accT[c] = __builtin_amdgcn_mfma_f32_16x16x32_bf16(zah, ybh, accT[c], 0, 0, 0);
                accT[c] = __builtin_amdgcn_mfma_f32_16x16x32_bf16(zah, ybl, accT[c], 0, 0, 0);
                accT[c] = __builtin_amdgcn_mfma_f32_16x16x32_bf16(zal, ybh, accT[c], 0, 0, 0);
            }
        }
        // WB W = 1.5I - 0.5T  (no barrier before: no wave reads W in phase 1)
#pragma unroll
        for (int c = 0; c < 4; c++) {
#pragma unroll
            for (int r = 0; r < 4; r++) {
                const int row = r0 + quad * 4 + r;       // C/D layout: row=quad*4+reg
                const int col = c * 16 + mrow;           //             col=lane&15
                float v = -0.5f * accT[c][r];
                if (row == col) v += 1.5f;
                const unsigned short h = f2bf(v);
                Wh[row * PP + col] = h;
                Wl[row * PP + col] = f2bf(v - bf2f(h));
            }
        }
        __syncthreads();   // sync1: W complete for all waves

        // ---- phase 2: Ynew = Y*W, Znew = W*Z (W carries the 1/2 factor) ----
        floatx4 accY[4], accZ[4];
#pragma unroll
        for (int c = 0; c < 4; c++) { accY[c] = zero4; accZ[c] = zero4; }
#pragma unroll
        for (int ks = 0; ks < 2; ks++) {
            const int ko = ks * 32 + quad * 8;
            const short8 yah = *(const short8*)&yh[(r0 + mrow) * PP + ko];
            const short8 yal = *(const short8*)&yl[(r0 + mrow) * PP + ko];
            const short8 wah = *(const short8*)&Wh[(r0 + mrow) * PP + ko];
            const short8 wal = *(const short8*)&Wl[(r0 + mrow) * PP + ko];
#pragma unroll
            for (int c = 0; c < 4; c++) {
                const short8 wbh = *(const short8*)&Wh[(c * 16 + mrow) * PP + ko];
                const short8 wbl = *(const short8*)&Wl[(c * 16 + mrow) * PP + ko];
                accY[c] = __builtin_amdgcn_mfma_f32_16x16x32_bf16(yah, wbh, accY[c], 0, 0, 0);
                accY[c] = __builtin_amdgcn_mfma_f32_16x16x32_bf16(yah, wbl, accY[c], 0, 0, 0);
                accY[c] = __builtin_amdgcn_mfma_f32_16x16x32_bf16(yal, wbh, accY[c], 0, 0, 0);
                const short8 zbh = *(const short8*)&zh[(c * 16 + mrow) * PP + ko];
                const short8 zbl = *(const short8*)&zl[(c * 16 + mrow) * PP + ko];
                accZ[c] = __builtin_amdgcn_mfma_f32_16x16x32_bf16(wah, zbh, accZ[c], 0, 0, 0);
                accZ[c] = __builtin_amdgcn_mfma_f32_16x16x32_bf16(wah, zbl, accZ[c], 0, 0, 0);
                accZ[c] = __builtin_amdgcn_mfma_f32_16x16x32_bf16(wal, zbh, accZ[c], 0, 0, 0);
            }
        }
        // WB to the ALTERNATE buffers (no anti-dependency -> no barrier before)
#pragma unroll
        for (int c = 0; c < 4; c++) {
#pragma unroll
            for (int r = 0; r < 4; r++) {
                const int row = r0 + quad * 4 + r;
                const int col = c * 16 + mrow;
                const float vy = accY[c][r];
                const float vz = accZ[c][r];
                unsigned short h = f2bf(vy);
                Yh[nxt][row * PP + col] = h;
                Yl[nxt][row * PP + col] = f2bf(vy - bf2f(h));
                h = f2bf(vz);
                Zh[nxt][row * PP + col] = h;
                Zl[nxt][row * PP + col] = f2bf(vz - bf2f(h));
            }
        }
        __syncthreads();   // sync2: Y',Z' complete for all waves
    }

    // trace(Y) * sqrt(c): hi+lo recovers ~16-bit mantissa per diag element
    const int fin = NS_ITERS & 1;
    if (tid < 64) {
        float d = bf2f(Yh[fin][tid * PP + tid]) + bf2f(Yl[fin][tid * PP + tid]);
#pragma unroll
        for (int off = 32; off; off >>= 1) d += __shfl_down(d, off, 64);
        if (tid == 0) atomicAdd(out, d * sqrtf(cnorm) * (1.0f / BN));
    }
}

extern "C" void kernel_launch(void* const* d_in, const int* in_sizes, int n_in,
                              void* d_out, int out_size, void* d_ws, size_t ws_size,
                              hipStream_t stream) {
    const float* x  = (const float*)d_in[0];
    const float* J  = (const float*)d_in[1];
    const int*   e0 = (const int*)d_in[2];
    const int*   e1 = (const int*)d_in[3];
    const int E = in_sizes[2];

    int*   row_ptr = (int*)d_ws;
    float* M       = (float*)((char*)d_ws + 128 * 1024);

    rowptr_kernel<<<(NV + 1 + 255) / 256, 256, 0, stream>>>(e0, E, row_ptr, M, (float*)d_out);
    node_kernel<<<dim3(512, BN), 256, 0, stream>>>(x, J, e1, row_ptr, M);
    ns_sqrt_kernel<<<BN, 256, 0, stream>>>(M, (float*)d_out);
}

// Round 7
// 253.020 us; speedup vs baseline: 1.6544x; 1.6544x over previous
//
#include <hip/hip_runtime.h>

constexpr int BN = 4;       // batches
constexpr int NV = 25600;   // vertices (160*160)
constexpr int DD = 64;      // D
constexpr int PP = 72;      // ns: bf16 LDS row pitch (b128-conflict-free, 16B-aligned)
constexpr int KP = 34;      // node: halfword pitch -> dword stride 17
constexpr int NS_ITERS = 13;

typedef __attribute__((ext_vector_type(8))) short short8;
typedef __attribute__((ext_vector_type(4))) float floatx4;

__device__ __forceinline__ unsigned short f2bf(float x) {
    unsigned u = __float_as_uint(x);
    u += 0x7fffu + ((u >> 16) & 1u);        // round-to-nearest-even
    return (unsigned short)(u >> 16);
}
__device__ __forceinline__ float bf2f(unsigned short h) {
    return __uint_as_float(((unsigned)h) << 16);
}

// rowptr + zero M + zero out (fused: fewer dispatches)
__global__ void rowptr_kernel(const int* __restrict__ e0, int E, int* __restrict__ row_ptr,
                              float* __restrict__ M, float* __restrict__ out) {
    int i = blockIdx.x * blockDim.x + threadIdx.x;
    if (i < BN * 64 * 64) M[i] = 0.f;
    if (i == 0) out[0] = 0.f;
    if (i > NV) return;
    int lo = 0, hi = E;
    while (lo < hi) {
        int mid = (lo + hi) >> 1;
        if (e0[mid] < i) lo = mid + 1; else hi = mid;
    }
    row_ptr[i] = lo;
}

// load an MFMA A/B fragment (8 consecutive halfwords) from a [64][KP] panel
__device__ __forceinline__ short8 ldfrag(const unsigned short* a, int row, int quad) {
    const unsigned* p = (const unsigned*)(a + row * KP + quad * 8);  // even offset -> uint-aligned
    union { unsigned u[4]; short8 s; } t;
    t.u[0] = p[0]; t.u[1] = p[1]; t.u[2] = p[2]; t.u[3] = p[3];
    return t.s;
}

// One wave per node (lane = d column). 4 nodes per block per chunk.
// launch_bounds (256,4): VGPR cap 128 -> compiler uses ~52, NO spills;
// HW occupancy self-selects 8 blocks/CU (VGPR 512/52 -> 8 waves/SIMD, LDS 17KB*8=139KB).
// Round-6 lesson: forcing (256,8) capped VGPR=32 and spilled 573 MB to scratch.
__global__ __launch_bounds__(256, 4) void node_kernel(
    const float* __restrict__ x, const float* __restrict__ J,
    const int* __restrict__ e1, const int* __restrict__ row_ptr,
    float* __restrict__ M)
{
    const int b    = blockIdx.y;
    const int w    = __builtin_amdgcn_readfirstlane(threadIdx.x >> 6);  // uniform wave id
    const int lane = threadIdx.x & 63;   // d index in phase 1
    const int quad = lane >> 4;
    const int mrow = lane & 15;
    const int r0   = w * 16;             // this wave's output row strip

    // A^T, B^T panels: [d/e][k], k=0..23 written each chunk, 24..31 stay zero
    __shared__ unsigned short ATh[64 * KP], ATl[64 * KP];
    __shared__ unsigned short BTh[64 * KP], BTl[64 * KP];

    for (int i = threadIdx.x; i < 64 * KP; i += 256) {
        ATh[i] = 0; ATl[i] = 0; BTh[i] = 0; BTl[i] = 0;
    }
    __syncthreads();

    const floatx4 zero4 = {0.f, 0.f, 0.f, 0.f};
    floatx4 accM[4];
#pragma unroll
    for (int c = 0; c < 4; c++) accM[c] = zero4;

    const float* xb = x + (size_t)b * NV * 3;
    const float* Jb = J + (size_t)b * 3 * NV * DD;

    for (int chunk = blockIdx.x; chunk < NV / 4; chunk += gridDim.x) {
        const int n   = chunk * 4 + w;
        const int beg = row_ptr[n];
        const int deg = row_ptr[n + 1] - beg;

        // neighbor indices (scalar loads; padded with self -> zero contribution)
        int mm[6];
#pragma unroll
        for (int k = 0; k < 6; k++) {
            const int idx = beg + ((k < deg) ? k : 0);
            const int mv  = e1[idx];
            mm[k] = (k < deg) ? mv : n;
        }

        // issue ALL global loads up front (one latency window)
        const float* Jn = Jb + n * 3 * DD + lane;
        const float jn0 = Jn[0], jn1 = Jn[DD], jn2 = Jn[2 * DD];
        float jm0[6], jm1[6], jm2[6];
#pragma unroll
        for (int k = 0; k < 6; k++) {
            const float* Jm = Jb + mm[k] * 3 * DD + lane;
            jm0[k] = Jm[0]; jm1[k] = Jm[DD]; jm2[k] = Jm[2 * DD];
        }
        const float xn0 = xb[n * 3 + 0], xn1 = xb[n * 3 + 1], xn2 = xb[n * 3 + 2];
        float va0[6], va1[6], va2[6];
#pragma unroll
        for (int k = 0; k < 6; k++) {
            va0[k] = xn0 - xb[mm[k] * 3 + 0];
            va1[k] = xn1 - xb[mm[k] * 3 + 1];
            va2[k] = xn2 - xb[mm[k] * 3 + 2];
        }

        float lj0 = 0, lj1 = 0, lj2 = 0, bt0 = 0, bt1 = 0, bt2 = 0;
        float cxx = 0, cxy = 0, cxz = 0, cyy = 0, cyz = 0, czz = 0;
#pragma unroll
        for (int k = 0; k < 6; k++) {
            const float v0 = va0[k], v1 = va1[k], v2 = va2[k];
            const float t0 = jm0[k] - jn0, t1 = jm1[k] - jn1, t2 = jm2[k] - jn2;
            lj0 -= t0; lj1 -= t1; lj2 -= t2;
            bt0 += v1 * t2 - v2 * t1;
            bt1 += v2 * t0 - v0 * t2;
            bt2 += v0 * t1 - v1 * t0;
            const float s2 = v0 * v0 + v1 * v1 + v2 * v2;
            cxx += s2 - v0 * v0; cyy += s2 - v1 * v1; czz += s2 - v2 * v2;
            cxy -= v0 * v1; cxz -= v0 * v2; cyz -= v1 * v2;
        }
        // safety tail (never taken on this mesh: max degree 6)
        for (int e = beg + 6; e < beg + deg; e++) {
            const int m = e1[e];
            const float v0 = xn0 - xb[m * 3 + 0];
            const float v1 = xn1 - xb[m * 3 + 1];
            const float v2 = xn2 - xb[m * 3 + 2];
            const float* Jm = Jb + m * 3 * DD + lane;
            const float t0 = Jm[0] - jn0, t1 = Jm[DD] - jn1, t2 = Jm[2 * DD] - jn2;
            lj0 -= t0; lj1 -= t1; lj2 -= t2;
            bt0 += v1 * t2 - v2 * t1;
            bt1 += v2 * t0 - v0 * t2;
            bt2 += v0 * t1 - v1 * t0;
            const float s2 = v0 * v0 + v1 * v1 + v2 * v2;
            cxx += s2 - v0 * v0; cyy += s2 - v1 * v1; czz += s2 - v2 * v2;
            cxy -= v0 * v1; cxz -= v0 * v2; cyz -= v1 * v2;
        }

        lj0 *= 2.f; lj1 *= 2.f; lj2 *= 2.f;
        const float co00 = cyy * czz - cyz * cyz;
        const float co01 = cxz * cyz - cxy * czz;
        const float co02 = cxy * cyz - cxz * cyy;
        const float det  = cxx * co00 + cxy * co01 + cxz * co02;
        const float id   = 1.0f / det;
        const float i00 = co00 * id, i01 = co01 * id, i02 = co02 * id;
        const float i11 = (cxx * czz - cxz * cxz) * id;
        const float i12 = (cxz * cxy - cxx * cyz) * id;
        const float i22 = (cxx * cyy - cxy * cxy) * id;
        const float cb0 = i00 * bt0 + i01 * bt1 + i02 * bt2;
        const float cb1 = i01 * bt0 + i11 * bt1 + i12 * bt2;
        const float cb2 = i02 * bt0 + i12 * bt1 + i22 * bt2;

        // transposed bf16 hi/lo writeback: row d=lane, k = w*6 + i
        {
            const int kA = w * 6;
            float av[6] = {jn0, jn1, jn2, bt0, bt1, bt2};
            float bv[6] = {lj0, lj1, lj2, -cb0, -cb1, -cb2};
#pragma unroll
            for (int i = 0; i < 6; i++) {
                unsigned short h = f2bf(av[i]);
                ATh[lane * KP + kA + i] = h;
                ATl[lane * KP + kA + i] = f2bf(av[i] - bf2f(h));
                h = f2bf(bv[i]);
                BTh[lane * KP + kA + i] = h;
                BTl[lane * KP + kA + i] = f2bf(bv[i] - bf2f(h));
            }
        }
        __syncthreads();

        // phase 2: 16x16x32 MFMA over K=32 (24 used), 4 col-tiles per wave
        const short8 ah = ldfrag(ATh, r0 + mrow, quad);
        const short8 al = ldfrag(ATl, r0 + mrow, quad);
#pragma unroll
        for (int c = 0; c < 4; c++) {
            const short8 bh = ldfrag(BTh, c * 16 + mrow, quad);
            const short8 bl = ldfrag(BTl, c * 16 + mrow, quad);
            accM[c] = __builtin_amdgcn_mfma_f32_16x16x32_bf16(ah, bh, accM[c], 0, 0, 0);
            accM[c] = __builtin_amdgcn_mfma_f32_16x16x32_bf16(ah, bl, accM[c], 0, 0, 0);
            accM[c] = __builtin_amdgcn_mfma_f32_16x16x32_bf16(al, bh, accM[c], 0, 0, 0);
        }
        __syncthreads();
    }

    float* Mb = M + b * 4096;
#pragma unroll
    for (int c = 0; c < 4; c++)
#pragma unroll
        for (int r = 0; r < 4; r++)
            atomicAdd(&Mb[(r0 + quad * 4 + r) * 64 + (c * 16 + mrow)], accM[c][r]);
}

// ---------------------------------------------------------------------------
// trace(sqrtm(M + delta*I)) via coupled Newton-Schulz, bf16-split MFMA matmuls.
// 4 waves (16-row strip each), double-buffered Y/Z (2 barriers/iter), and the
// hh/hl/lh split accumulated into 3 INDEPENDENT chains (depth 6 -> 2) merged
// with fp32 adds at writeback -> 12-36 independent MFMA chains to hide latency
// at 1 wave/SIMD.  c = ||M||_F (tight lambda_max bound) -> 13 iters suffice:
// anything unconverged by 13 has lambda/c < 3e-4 and trace deficit < ~10.
// ---------------------------------------------------------------------------
__global__ __launch_bounds__(256, 1) void ns_sqrt_kernel(const float* __restrict__ M,
                                                         float* __restrict__ out)
{
    const int b    = blockIdx.x;
    const int tid  = threadIdx.x;
    const int w    = tid >> 6;
    const int lane = tid & 63;
    const int quad = lane >> 4;
    const int mrow = lane & 15;
    const int r0   = w * 16;             // this wave's output row strip

    __shared__ __align__(16) unsigned short Yh[2][64 * PP], Yl[2][64 * PP];
    __shared__ __align__(16) unsigned short Zh[2][64 * PP], Zl[2][64 * PP];
    __shared__ __align__(16) unsigned short Wh[64 * PP], Wl[64 * PP];
    __shared__ float red_s[4];
    __shared__ float tr_s;

    const float* Mb = M + b * 4096;

    // trace + Frobenius norm of M
    {
        float f2 = 0.f;
        for (int i = tid; i < 4096; i += 256) { const float v = Mb[i]; f2 += v * v; }
#pragma unroll
        for (int off = 32; off; off >>= 1) f2 += __shfl_down(f2, off, 64);
        if (lane == 0) red_s[w] = f2;
        if (tid < 64) {
            float d = Mb[tid * 64 + tid];
#pragma unroll
            for (int off = 32; off; off >>= 1) d += __shfl_down(d, off, 64);
            if (tid == 0) tr_s = d;
        }
    }
    __syncthreads();
    const float tr    = tr_s;
    const float fro   = sqrtf(red_s[0] + red_s[1] + red_s[2] + red_s[3]);
    const float delta = 3e-5f * tr;
    const float cnorm = fro + 2.f * delta;   // >= lambda_max(M + delta I)
    const float inv_c = 1.f / cnorm;

    // Y0 = (M + delta I)/c  (bf16 hi/lo split), Z0 = I  -> buffer 0
    for (int i = tid; i < 4096; i += 256) {
        const int r = i >> 6, col = i & 63;
        float v = Mb[i] * inv_c;
        if (r == col) v += delta * inv_c;
        const unsigned short h = f2bf(v);
        Yh[0][r * PP + col] = h;
        Yl[0][r * PP + col] = f2bf(v - bf2f(h));
        Zh[0][r * PP + col] = (r == col) ? (unsigned short)0x3f80 : (unsigned short)0;
        Zl[0][r * PP + col] = 0;
    }
    __syncthreads();

    const floatx4 zero4 = {0.f, 0.f, 0.f, 0.f};

    for (int it = 0; it < NS_ITERS; ++it) {
        const int cur = it & 1, nxt = cur ^ 1;
        const unsigned short* yh = Yh[cur]; const unsigned short* yl = Yl[cur];
        const unsigned short* zh = Zh[cur]; const unsigned short* zl = Zl[cur];

        // ---- phase 1: T = Z*Y, 3 independent chains per tile ----
        floatx4 t0[4], t1[4], t2[4];
#pragma unroll
        for (int c = 0; c < 4; c++) { t0[c] = zero4; t1[c] = zero4; t2[c] = zero4; }
#pragma unroll
        for (int ks = 0; ks < 2; ks++) {
            const int ko = ks * 32 + quad * 8;
            const short8 zah = *(const short8*)&zh[(r0 + mrow) * PP + ko];
            const short8 zal = *(const short8*)&zl[(r0 + mrow) * PP + ko];
#pragma unroll
            for (int c = 0; c < 4; c++) {
                const short8 ybh = *(const short8*)&yh[(c * 16 + mrow) * PP + ko];
                const short8 ybl = *(const short8*)&yl[(c * 16 + mrow) * PP + ko];
                t0[c] = __builtin_amdgcn_mfma_f32_16x16x32_bf16(zah, ybh, t0[c], 0, 0, 0);
                t1[c] = __builtin_amdgcn_mfma_f32_16x16x32_bf16(zah, ybl, t1[c], 0, 0, 0);
                t2[c] = __builtin_amdgcn_mfma_f32_16x16x32_bf16(zal, ybh, t2[c], 0, 0, 0);
            }
        }
        // WB W = 1.5I - 0.5T  (no barrier before: no wave reads W in phase 1)
#pragma unroll
        for (int c = 0; c < 4; c++) {
#pragma unroll
            for (int r = 0; r < 4; r++) {
                const int row = r0 + quad * 4 + r;       // C/D layout: row=quad*4+reg
                const int col = c * 16 + mrow;           //             col=lane&15
                float v = -0.5f * (t0[c][r] + t1[c][r] + t2[c][r]);
                if (row == col) v += 1.5f;
                const unsigned short h = f2bf(v);
                Wh[row * PP + col] = h;
                Wl[row * PP + col] = f2bf(v - bf2f(h));
            }
        }
        __syncthreads();   // sync1: W complete for all waves

        // ---- phase 2: Ynew = Y*W, Znew = W*Z (W carries the 1/2 factor) ----
        floatx4 y0[4], y1[4], y2[4], z0[4], z1[4], z2[4];
#pragma unroll
        for (int c = 0; c < 4; c++) {
            y0[c] = zero4; y1[c] = zero4; y2[c] = zero4;
            z0[c] = zero4; z1[c] = zero4; z2[c] = zero4;
        }
#pragma unroll
        for (int ks = 0; ks < 2; ks++) {
            const int ko = ks * 32 + quad * 8;
            const short8 yah = *(const short8*)&yh[(r0 + mrow) * PP + ko];
            const short8 yal = *(const short8*)&yl[(r0 + mrow) * PP + ko];
            const short8 wah = *(const short8*)&Wh[(r0 + mrow) * PP + ko];
            const short8 wal = *(const short8*)&Wl[(r0 + mrow) * PP + ko];
#pragma unroll
            for (int c = 0; c < 4; c++) {
                const short8 wbh = *(const short8*)&Wh[(c * 16 + mrow) * PP + ko];
                const short8 wbl = *(const short8*)&Wl[(c * 16 + mrow) * PP + ko];
                y0[c] = __builtin_amdgcn_mfma_f32_16x16x32_bf16(yah, wbh, y0[c], 0, 0, 0);
                y1[c] = __builtin_amdgcn_mfma_f32_16x16x32_bf16(yah, wbl, y1[c], 0, 0, 0);
                y2[c] = __builtin_amdgcn_mfma_f32_16x16x32_bf16(yal, wbh, y2[c], 0, 0, 0);
                const short8 zbh = *(const short8*)&zh[(c * 16 + mrow) * PP + ko];
                const short8 zbl = *(const short8*)&zl[(c * 16 + mrow) * PP + ko];
                z0[c] = __builtin_amdgcn_mfma_f32_16x16x32_bf16(wah, zbh, z0[c], 0, 0, 0);
                z1[c] = __builtin_amdgcn_mfma_f32_16x16x32_bf16(wah, zbl, z1[c], 0, 0, 0);
                z2[c] = __builtin_amdgcn_mfma_f32_16x16x32_bf16(wal, zbh, z2[c], 0, 0, 0);
            }
        }
        // WB to the ALTERNATE buffers (no anti-dependency -> no barrier before)
#pragma unroll
        for (int c = 0; c < 4; c++) {
#pragma unroll
            for (int r = 0; r < 4; r++) {
                const int row = r0 + quad * 4 + r;
                const int col = c * 16 + mrow;
                const float vy = y0[c][r] + y1[c][r] + y2[c][r];
                const float vz = z0[c][r] + z1[c][r] + z2[c][r];
                unsigned short h = f2bf(vy);
                Yh[nxt][row * PP + col] = h;
                Yl[nxt][row * PP + col] = f2bf(vy - bf2f(h));
                h = f2bf(vz);
                Zh[nxt][row * PP + col] = h;
                Zl[nxt][row * PP + col] = f2bf(vz - bf2f(h));
            }
        }
        __syncthreads();   // sync2: Y',Z' complete for all waves
    }

    // trace(Y) * sqrt(c): hi+lo recovers ~16-bit mantissa per diag element
    const int fin = NS_ITERS & 1;
    if (tid < 64) {
        float d = bf2f(Yh[fin][tid * PP + tid]) + bf2f(Yl[fin][tid * PP + tid]);
#pragma unroll
        for (int off = 32; off; off >>= 1) d += __shfl_down(d, off, 64);
        if (tid == 0) atomicAdd(out, d * sqrtf(cnorm) * (1.0f / BN));
    }
}

extern "C" void kernel_launch(void* const* d_in, const int* in_sizes, int n_in,
                              void* d_out, int out_size, void* d_ws, size_t ws_size,
                              hipStream_t stream) {
    const float* x  = (const float*)d_in[0];
    const float* J  = (const float*)d_in[1];
    const int*   e0 = (const int*)d_in[2];
    const int*   e1 = (const int*)d_in[3];
    const int E = in_sizes[2];

    int*   row_ptr = (int*)d_ws;
    float* M       = (float*)((char*)d_ws + 128 * 1024);

    rowptr_kernel<<<(NV + 1 + 255) / 256, 256, 0, stream>>>(e0, E, row_ptr, M, (float*)d_out);
    node_kernel<<<dim3(512, BN), 256, 0, stream>>>(x, J, e1, row_ptr, M);
    ns_sqrt_kernel<<<BN, 256, 0, stream>>>(M, (float*)d_out);
}

// Round 8
// 237.707 us; speedup vs baseline: 1.7609x; 1.0644x over previous
//
#include <hip/hip_runtime.h>

constexpr int BN = 4;       // batches
constexpr int NV = 25600;   // vertices (160*160)
constexpr int DD = 64;      // D
constexpr int PP = 72;      // ns: bf16 LDS row pitch
constexpr int KP = 34;      // node: halfword pitch -> dword stride 17 (2-way = free on writes)
constexpr int NS_ITERS = 13;
constexpr size_t GEOM_OFF = 1u << 20;   // geometry scratch at ws+1MB, 28 floats/(b,node)

typedef __attribute__((ext_vector_type(8))) short short8;
typedef __attribute__((ext_vector_type(4))) float floatx4;

__device__ __forceinline__ unsigned short f2bf(float x) {
    unsigned u = __float_as_uint(x);
    u += 0x7fffu + ((u >> 16) & 1u);        // round-to-nearest-even
    return (unsigned short)(u >> 16);
}
__device__ __forceinline__ float bf2f(unsigned short h) {
    return __uint_as_float(((unsigned)h) << 16);
}
__device__ __forceinline__ unsigned pack2bf(float a, float b) {
    return (unsigned)f2bf(a) | ((unsigned)f2bf(b) << 16);
}

// rowptr + zero M + zero out
__global__ void rowptr_kernel(const int* __restrict__ e0, int E, int* __restrict__ row_ptr,
                              float* __restrict__ M, float* __restrict__ out) {
    int i = blockIdx.x * blockDim.x + threadIdx.x;
    if (i < BN * 64 * 64) M[i] = 0.f;
    if (i == 0) out[0] = 0.f;
    if (i > NV) return;
    int lo = 0, hi = E;
    while (lo < hi) {
        int mid = (lo + hi) >> 1;
        if (e0[mid] < i) lo = mid + 1; else hi = mid;
    }
    row_ptr[i] = lo;
}

// Per-(batch,node) geometry: v[6][3], sum(v)[3], Cinv[6] -> 28 floats.
// Layout g[0..17]=v, g[18..20]=sv, g[21..26]=cinv(i00,i01,i02,i11,i12,i22), g[27]=pad.
__global__ __launch_bounds__(256) void geom_kernel(
    const float* __restrict__ x, const int* __restrict__ e1,
    const int* __restrict__ row_ptr, float* __restrict__ geom)
{
    const int gid = blockIdx.x * 256 + threadIdx.x;
    if (gid >= BN * NV) return;
    const int b = gid / NV;
    const int n = gid - b * NV;
    const float* xb = x + (size_t)b * NV * 3;
    const int beg = row_ptr[n];
    const int deg = row_ptr[n + 1] - beg;
    const float xn0 = xb[n * 3], xn1 = xb[n * 3 + 1], xn2 = xb[n * 3 + 2];
    float v[6][3];
    float sv0 = 0, sv1 = 0, sv2 = 0;
    float cxx = 0, cxy = 0, cxz = 0, cyy = 0, cyz = 0, czz = 0;
#pragma unroll
    for (int k = 0; k < 6; k++) {
        const int m = (k < deg) ? e1[beg + k] : n;   // m=n -> v=0 exactly
        const float v0 = xn0 - xb[m * 3];
        const float v1 = xn1 - xb[m * 3 + 1];
        const float v2 = xn2 - xb[m * 3 + 2];
        v[k][0] = v0; v[k][1] = v1; v[k][2] = v2;
        sv0 += v0; sv1 += v1; sv2 += v2;
        const float s2 = v0 * v0 + v1 * v1 + v2 * v2;
        cxx += s2 - v0 * v0; cyy += s2 - v1 * v1; czz += s2 - v2 * v2;
        cxy -= v0 * v1; cxz -= v0 * v2; cyz -= v1 * v2;
    }
    const float co00 = cyy * czz - cyz * cyz;
    const float co01 = cxz * cyz - cxy * czz;
    const float co02 = cxy * cyz - cxz * cyy;
    const float det  = cxx * co00 + cxy * co01 + cxz * co02;
    const float id   = 1.0f / det;
    const float i00 = co00 * id, i01 = co01 * id, i02 = co02 * id;
    const float i11 = (cxx * czz - cxz * cxz) * id;
    const float i12 = (cxz * cxy - cxx * cyz) * id;
    const float i22 = (cxx * cyy - cxy * cxy) * id;

    float4* g4 = (float4*)(geom + (size_t)gid * 28);
    g4[0] = make_float4(v[0][0], v[0][1], v[0][2], v[1][0]);
    g4[1] = make_float4(v[1][1], v[1][2], v[2][0], v[2][1]);
    g4[2] = make_float4(v[2][2], v[3][0], v[3][1], v[3][2]);
    g4[3] = make_float4(v[4][0], v[4][1], v[4][2], v[5][0]);
    g4[4] = make_float4(v[5][1], v[5][2], sv0, sv1);
    g4[5] = make_float4(sv2, i00, i01, i02);
    g4[6] = make_float4(i11, i12, i22, 0.f);
}

// fragment load from a [64][KP-halfword] panel
__device__ __forceinline__ short8 ldfrag(const unsigned short* a, int row, int quad) {
    const unsigned* p = (const unsigned*)(a + row * KP + quad * 8);
    union { unsigned u[4]; short8 s; } t;
    t.u[0] = p[0]; t.u[1] = p[1]; t.u[2] = p[2]; t.u[3] = p[3];
    return t.s;
}

// FAST node kernel: per-node geometry from scratch (scalar pipe), single-bf16
// Gram panels (RNE errors on 25600-term sums average out: ~1e-5 rel on M).
__global__ __launch_bounds__(256, 4) void node_kernel_fast(
    const float* __restrict__ J, const int* __restrict__ e1,
    const int* __restrict__ row_ptr, const float* __restrict__ geom,
    float* __restrict__ M)
{
    const int b    = blockIdx.y;
    const int w    = __builtin_amdgcn_readfirstlane(threadIdx.x >> 6);
    const int lane = threadIdx.x & 63;
    const int quad = lane >> 4;
    const int mrow = lane & 15;
    const int r0   = w * 16;

    __shared__ unsigned short ATh[64 * KP];
    __shared__ unsigned short BTh[64 * KP];
    for (int i = threadIdx.x; i < 64 * KP; i += 256) { ATh[i] = 0; BTh[i] = 0; }
    __syncthreads();

    const floatx4 zero4 = {0.f, 0.f, 0.f, 0.f};
    floatx4 accM[4];
#pragma unroll
    for (int c = 0; c < 4; c++) accM[c] = zero4;

    const float* Jb = J + (size_t)b * 3 * NV * DD;

    for (int chunk = blockIdx.x; chunk < NV / 4; chunk += gridDim.x) {
        const int n   = chunk * 4 + w;                       // uniform
        const int beg = row_ptr[n];
        const int deg = row_ptr[n + 1] - beg;
        const float* g = geom + (size_t)(b * NV + n) * 28;   // uniform -> scalar loads

        int mm[6];
#pragma unroll
        for (int k = 0; k < 6; k++) {
            const int idx = beg + ((k < deg) ? k : 0);
            const int mv  = e1[idx];
            mm[k] = (k < deg) ? mv : n;
        }

        const float* Jn = Jb + n * 3 * DD + lane;
        const float jn0 = Jn[0], jn1 = Jn[DD], jn2 = Jn[2 * DD];
        float jm0[6], jm1[6], jm2[6];
#pragma unroll
        for (int k = 0; k < 6; k++) {
            const float* Jm = Jb + mm[k] * 3 * DD + lane;
            jm0[k] = Jm[0]; jm1[k] = Jm[DD]; jm2[k] = Jm[2 * DD];
        }

        // lj = 2*(6*jn - sum(jm))   (padded jm = jn keeps this exact)
        const float sm0 = (jm0[0] + jm0[1]) + (jm0[2] + jm0[3]) + (jm0[4] + jm0[5]);
        const float sm1 = (jm1[0] + jm1[1]) + (jm1[2] + jm1[3]) + (jm1[4] + jm1[5]);
        const float sm2 = (jm2[0] + jm2[1]) + (jm2[2] + jm2[3]) + (jm2[4] + jm2[5]);
        const float lj0 = 12.f * jn0 - 2.f * sm0;
        const float lj1 = 12.f * jn1 - 2.f * sm1;
        const float lj2 = 12.f * jn2 - 2.f * sm2;

        // bt = sum_k v_k x jm_k - sv x jn   (padded v_k = 0)
        const float sv0 = g[18], sv1 = g[19], sv2 = g[20];
        float bt0 = sv2 * jn1 - sv1 * jn2;
        float bt1 = sv0 * jn2 - sv2 * jn0;
        float bt2 = sv1 * jn0 - sv0 * jn1;
#pragma unroll
        for (int k = 0; k < 6; k++) {
            const float v0 = g[k * 3], v1 = g[k * 3 + 1], v2 = g[k * 3 + 2];
            bt0 += v1 * jm2[k] - v2 * jm1[k];
            bt1 += v2 * jm0[k] - v0 * jm2[k];
            bt2 += v0 * jm1[k] - v1 * jm0[k];
        }

        const float i00 = g[21], i01 = g[22], i02 = g[23];
        const float i11 = g[24], i12 = g[25], i22 = g[26];
        const float cb0 = i00 * bt0 + i01 * bt1 + i02 * bt2;
        const float cb1 = i01 * bt0 + i11 * bt1 + i12 * bt2;
        const float cb2 = i02 * bt0 + i12 * bt1 + i22 * bt2;

        // packed single-bf16 writeback: 3 dwords per panel per lane
        {
            const int base = lane * (KP / 2) + w * 3;   // dword index; stride 17 -> 2-way free
            unsigned* A32 = (unsigned*)ATh;
            unsigned* B32 = (unsigned*)BTh;
            A32[base + 0] = pack2bf(jn0, jn1);
            A32[base + 1] = pack2bf(jn2, bt0);
            A32[base + 2] = pack2bf(bt1, bt2);
            B32[base + 0] = pack2bf(lj0, lj1);
            B32[base + 1] = pack2bf(lj2, -cb0);
            B32[base + 2] = pack2bf(-cb1, -cb2);
        }
        __syncthreads();

        // phase 2: 4 MFMAs (16x16x32, K=32 with zero pad at k>=24)
        const short8 ah = ldfrag(ATh, r0 + mrow, quad);
#pragma unroll
        for (int c = 0; c < 4; c++) {
            const short8 bh = ldfrag(BTh, c * 16 + mrow, quad);
            accM[c] = __builtin_amdgcn_mfma_f32_16x16x32_bf16(ah, bh, accM[c], 0, 0, 0);
        }
        __syncthreads();
    }

    float* Mb = M + b * 4096;
#pragma unroll
    for (int c = 0; c < 4; c++)
#pragma unroll
        for (int r = 0; r < 4; r++)
            atomicAdd(&Mb[(r0 + quad * 4 + r) * 64 + (c * 16 + mrow)], accM[c][r]);
}

// SLOW fallback (round-7 proven path, used only if ws too small for geometry)
__global__ __launch_bounds__(256, 4) void node_kernel_slow(
    const float* __restrict__ x, const float* __restrict__ J,
    const int* __restrict__ e1, const int* __restrict__ row_ptr,
    float* __restrict__ M)
{
    const int b    = blockIdx.y;
    const int w    = __builtin_amdgcn_readfirstlane(threadIdx.x >> 6);
    const int lane = threadIdx.x & 63;
    const int quad = lane >> 4;
    const int mrow = lane & 15;
    const int r0   = w * 16;

    __shared__ unsigned short ATh[64 * KP], ATl[64 * KP];
    __shared__ unsigned short BTh[64 * KP], BTl[64 * KP];
    for (int i = threadIdx.x; i < 64 * KP; i += 256) { ATh[i]=0; ATl[i]=0; BTh[i]=0; BTl[i]=0; }
    __syncthreads();

    const floatx4 zero4 = {0.f, 0.f, 0.f, 0.f};
    floatx4 accM[4];
#pragma unroll
    for (int c = 0; c < 4; c++) accM[c] = zero4;

    const float* xb = x + (size_t)b * NV * 3;
    const float* Jb = J + (size_t)b * 3 * NV * DD;

    for (int chunk = blockIdx.x; chunk < NV / 4; chunk += gridDim.x) {
        const int n   = chunk * 4 + w;
        const int beg = row_ptr[n];
        const int deg = row_ptr[n + 1] - beg;
        int mm[6];
#pragma unroll
        for (int k = 0; k < 6; k++) {
            const int idx = beg + ((k < deg) ? k : 0);
            const int mv  = e1[idx];
            mm[k] = (k < deg) ? mv : n;
        }
        const float* Jn = Jb + n * 3 * DD + lane;
        const float jn0 = Jn[0], jn1 = Jn[DD], jn2 = Jn[2 * DD];
        float jm0[6], jm1[6], jm2[6];
#pragma unroll
        for (int k = 0; k < 6; k++) {
            const float* Jm = Jb + mm[k] * 3 * DD + lane;
            jm0[k] = Jm[0]; jm1[k] = Jm[DD]; jm2[k] = Jm[2 * DD];
        }
        const float xn0 = xb[n * 3 + 0], xn1 = xb[n * 3 + 1], xn2 = xb[n * 3 + 2];
        float va0[6], va1[6], va2[6];
#pragma unroll
        for (int k = 0; k < 6; k++) {
            va0[k] = xn0 - xb[mm[k] * 3 + 0];
            va1[k] = xn1 - xb[mm[k] * 3 + 1];
            va2[k] = xn2 - xb[mm[k] * 3 + 2];
        }
        float lj0=0, lj1=0, lj2=0, bt0=0, bt1=0, bt2=0;
        float cxx=0, cxy=0, cxz=0, cyy=0, cyz=0, czz=0;
#pragma unroll
        for (int k = 0; k < 6; k++) {
            const float v0 = va0[k], v1 = va1[k], v2 = va2[k];
            const float t0 = jm0[k]-jn0, t1 = jm1[k]-jn1, t2 = jm2[k]-jn2;
            lj0 -= t0; lj1 -= t1; lj2 -= t2;
            bt0 += v1*t2 - v2*t1; bt1 += v2*t0 - v0*t2; bt2 += v0*t1 - v1*t0;
            const float s2 = v0*v0 + v1*v1 + v2*v2;
            cxx += s2 - v0*v0; cyy += s2 - v1*v1; czz += s2 - v2*v2;
            cxy -= v0*v1; cxz -= v0*v2; cyz -= v1*v2;
        }
        lj0 *= 2.f; lj1 *= 2.f; lj2 *= 2.f;
        const float co00 = cyy*czz - cyz*cyz;
        const float co01 = cxz*cyz - cxy*czz;
        const float co02 = cxy*cyz - cxz*cyy;
        const float det  = cxx*co00 + cxy*co01 + cxz*co02;
        const float id   = 1.0f / det;
        const float i00 = co00*id, i01 = co01*id, i02 = co02*id;
        const float i11 = (cxx*czz - cxz*cxz)*id;
        const float i12 = (cxz*cxy - cxx*cyz)*id;
        const float i22 = (cxx*cyy - cxy*cxy)*id;
        const float cb0 = i00*bt0 + i01*bt1 + i02*bt2;
        const float cb1 = i01*bt0 + i11*bt1 + i12*bt2;
        const float cb2 = i02*bt0 + i12*bt1 + i22*bt2;
        {
            const int kA = w * 6;
            float av[6] = {jn0, jn1, jn2, bt0, bt1, bt2};
            float bv[6] = {lj0, lj1, lj2, -cb0, -cb1, -cb2};
#pragma unroll
            for (int i = 0; i < 6; i++) {
                unsigned short h = f2bf(av[i]);
                ATh[lane*KP + kA + i] = h; ATl[lane*KP + kA + i] = f2bf(av[i] - bf2f(h));
                h = f2bf(bv[i]);
                BTh[lane*KP + kA + i] = h; BTl[lane*KP + kA + i] = f2bf(bv[i] - bf2f(h));
            }
        }
        __syncthreads();
        const short8 ah = ldfrag(ATh, r0 + mrow, quad);
        const short8 al = ldfrag(ATl, r0 + mrow, quad);
#pragma unroll
        for (int c = 0; c < 4; c++) {
            const short8 bh = ldfrag(BTh, c*16 + mrow, quad);
            const short8 bl = ldfrag(BTl, c*16 + mrow, quad);
            accM[c] = __builtin_amdgcn_mfma_f32_16x16x32_bf16(ah, bh, accM[c], 0, 0, 0);
            accM[c] = __builtin_amdgcn_mfma_f32_16x16x32_bf16(ah, bl, accM[c], 0, 0, 0);
            accM[c] = __builtin_amdgcn_mfma_f32_16x16x32_bf16(al, bh, accM[c], 0, 0, 0);
        }
        __syncthreads();
    }
    float* Mb = M + b * 4096;
#pragma unroll
    for (int c = 0; c < 4; c++)
#pragma unroll
        for (int r = 0; r < 4; r++)
            atomicAdd(&Mb[(r0 + quad*4 + r) * 64 + (c*16 + mrow)], accM[c][r]);
}

// ---------------------------------------------------------------------------
// trace(sqrtm(M + delta*I)) via coupled Newton-Schulz (unchanged from round 7)
// ---------------------------------------------------------------------------
__global__ __launch_bounds__(256, 1) void ns_sqrt_kernel(const float* __restrict__ M,
                                                         float* __restrict__ out)
{
    const int b    = blockIdx.x;
    const int tid  = threadIdx.x;
    const int w    = tid >> 6;
    const int lane = tid & 63;
    const int quad = lane >> 4;
    const int mrow = lane & 15;
    const int r0   = w * 16;

    __shared__ __align__(16) unsigned short Yh[2][64 * PP], Yl[2][64 * PP];
    __shared__ __align__(16) unsigned short Zh[2][64 * PP], Zl[2][64 * PP];
    __shared__ __align__(16) unsigned short Wh[64 * PP], Wl[64 * PP];
    __shared__ float red_s[4];
    __shared__ float tr_s;

    const float* Mb = M + b * 4096;

    {
        float f2 = 0.f;
        for (int i = tid; i < 4096; i += 256) { const float v = Mb[i]; f2 += v * v; }
#pragma unroll
        for (int off = 32; off; off >>= 1) f2 += __shfl_down(f2, off, 64);
        if (lane == 0) red_s[w] = f2;
        if (tid < 64) {
            float d = Mb[tid * 64 + tid];
#pragma unroll
            for (int off = 32; off; off >>= 1) d += __shfl_down(d, off, 64);
            if (tid == 0) tr_s = d;
        }
    }
    __syncthreads();
    const float tr    = tr_s;
    const float fro   = sqrtf(red_s[0] + red_s[1] + red_s[2] + red_s[3]);
    const float delta = 3e-5f * tr;
    const float cnorm = fro + 2.f * delta;
    const float inv_c = 1.f / cnorm;

    for (int i = tid; i < 4096; i += 256) {
        const int r = i >> 6, col = i & 63;
        float v = Mb[i] * inv_c;
        if (r == col) v += delta * inv_c;
        const unsigned short h = f2bf(v);
        Yh[0][r * PP + col] = h;
        Yl[0][r * PP + col] = f2bf(v - bf2f(h));
        Zh[0][r * PP + col] = (r == col) ? (unsigned short)0x3f80 : (unsigned short)0;
        Zl[0][r * PP + col] = 0;
    }
    __syncthreads();

    const floatx4 zero4 = {0.f, 0.f, 0.f, 0.f};

    for (int it = 0; it < NS_ITERS; ++it) {
        const int cur = it & 1, nxt = cur ^ 1;
        const unsigned short* yh = Yh[cur]; const unsigned short* yl = Yl[cur];
        const unsigned short* zh = Zh[cur]; const unsigned short* zl = Zl[cur];

        floatx4 t0[4], t1[4], t2[4];
#pragma unroll
        for (int c = 0; c < 4; c++) { t0[c] = zero4; t1[c] = zero4; t2[c] = zero4; }
#pragma unroll
        for (int ks = 0; ks < 2; ks++) {
            const int ko = ks * 32 + quad * 8;
            const short8 zah = *(const short8*)&zh[(r0 + mrow) * PP + ko];
            const short8 zal = *(const short8*)&zl[(r0 + mrow) * PP + ko];
#pragma unroll
            for (int c = 0; c < 4; c++) {
                const short8 ybh = *(const short8*)&yh[(c * 16 + mrow) * PP + ko];
                const short8 ybl = *(const short8*)&yl[(c * 16 + mrow) * PP + ko];
                t0[c] = __builtin_amdgcn_mfma_f32_16x16x32_bf16(zah, ybh, t0[c], 0, 0, 0);
                t1[c] = __builtin_amdgcn_mfma_f32_16x16x32_bf16(zah, ybl, t1[c], 0, 0, 0);
                t2[c] = __builtin_amdgcn_mfma_f32_16x16x32_bf16(zal, ybh, t2[c], 0, 0, 0);
            }
        }
#pragma unroll
        for (int c = 0; c < 4; c++) {
#pragma unroll
            for (int r = 0; r < 4; r++) {
                const int row = r0 + quad * 4 + r;
                const int col = c * 16 + mrow;
                float v = -0.5f * (t0[c][r] + t1[c][r] + t2[c][r]);
                if (row == col) v += 1.5f;
                const unsigned short h = f2bf(v);
                Wh[row * PP + col] = h;
                Wl[row * PP + col] = f2bf(v - bf2f(h));
            }
        }
        __syncthreads();

        floatx4 y0[4], y1[4], y2[4], z0[4], z1[4], z2[4];
#pragma unroll
        for (int c = 0; c < 4; c++) {
            y0[c] = zero4; y1[c] = zero4; y2[c] = zero4;
            z0[c] = zero4; z1[c] = zero4; z2[c] = zero4;
        }
#pragma unroll
        for (int ks = 0; ks < 2; ks++) {
            const int ko = ks * 32 + quad * 8;
            const short8 yah = *(const short8*)&yh[(r0 + mrow) * PP + ko];
            const short8 yal = *(const short8*)&yl[(r0 + mrow) * PP + ko];
            const short8 wah = *(const short8*)&Wh[(r0 + mrow) * PP + ko];
            const short8 wal = *(const short8*)&Wl[(r0 + mrow) * PP + ko];
#pragma unroll
            for (int c = 0; c < 4; c++) {
                const short8 wbh = *(const short8*)&Wh[(c * 16 + mrow) * PP + ko];
                const short8 wbl = *(const short8*)&Wl[(c * 16 + mrow) * PP + ko];
                y0[c] = __builtin_amdgcn_mfma_f32_16x16x32_bf16(yah, wbh, y0[c], 0, 0, 0);
                y1[c] = __builtin_amdgcn_mfma_f32_16x16x32_bf16(yah, wbl, y1[c], 0, 0, 0);
                y2[c] = __builtin_amdgcn_mfma_f32_16x16x32_bf16(yal, wbh, y2[c], 0, 0, 0);
                const short8 zbh = *(const short8*)&zh[(c * 16 + mrow) * PP + ko];
                const short8 zbl = *(const short8*)&zl[(c * 16 + mrow) * PP + ko];
                z0[c] = __builtin_amdgcn_mfma_f32_16x16x32_bf16(wah, zbh, z0[c], 0, 0, 0);
                z1[c] = __builtin_amdgcn_mfma_f32_16x16x32_bf16(wah, zbl, z1[c], 0, 0, 0);
                z2[c] = __builtin_amdgcn_mfma_f32_16x16x32_bf16(wal, zbh, z2[c], 0, 0, 0);
            }
        }
#pragma unroll
        for (int c = 0; c < 4; c++) {
#pragma unroll
            for (int r = 0; r < 4; r++) {
                const int row = r0 + quad * 4 + r;
                const int col = c * 16 + mrow;
                const float vy = y0[c][r] + y1[c][r] + y2[c][r];
                const float vz = z0[c][r] + z1[c][r] + z2[c][r];
                unsigned short h = f2bf(vy);
                Yh[nxt][row * PP + col] = h;
                Yl[nxt][row * PP + col] = f2bf(vy - bf2f(h));
                h = f2bf(vz);
                Zh[nxt][row * PP + col] = h;
                Zl[nxt][row * PP + col] = f2bf(vz - bf2f(h));
            }
        }
        __syncthreads();
    }

    const int fin = NS_ITERS & 1;
    if (tid < 64) {
        float d = bf2f(Yh[fin][tid * PP + tid]) + bf2f(Yl[fin][tid * PP + tid]);
#pragma unroll
        for (int off = 32; off; off >>= 1) d += __shfl_down(d, off, 64);
        if (tid == 0) atomicAdd(out, d * sqrtf(cnorm) * (1.0f / BN));
    }
}

extern "C" void kernel_launch(void* const* d_in, const int* in_sizes, int n_in,
                              void* d_out, int out_size, void* d_ws, size_t ws_size,
                              hipStream_t stream) {
    const float* x  = (const float*)d_in[0];
    const float* J  = (const float*)d_in[1];
    const int*   e0 = (const int*)d_in[2];
    const int*   e1 = (const int*)d_in[3];
    const int E = in_sizes[2];

    int*   row_ptr = (int*)d_ws;
    float* M       = (float*)((char*)d_ws + 128 * 1024);
    float* geom    = (float*)((char*)d_ws + GEOM_OFF);
    const size_t need = GEOM_OFF + (size_t)BN * NV * 28 * sizeof(float);

    rowptr_kernel<<<(NV + 1 + 255) / 256, 256, 0, stream>>>(e0, E, row_ptr, M, (float*)d_out);
    if (ws_size >= need) {
        geom_kernel<<<(BN * NV + 255) / 256, 256, 0, stream>>>(x, e1, row_ptr, geom);
        node_kernel_fast<<<dim3(512, BN), 256, 0, stream>>>(J, e1, row_ptr, geom, M);
    } else {
        node_kernel_slow<<<dim3(512, BN), 256, 0, stream>>>(x, J, e1, row_ptr, M);
    }
    ns_sqrt_kernel<<<BN, 256, 0, stream>>>(M, (float*)d_out);
}

// Round 9
// 226.348 us; speedup vs baseline: 1.8493x; 1.0502x over previous
//
#include <hip/hip_runtime.h>

constexpr int BN = 4;       // batches
constexpr int NV = 25600;   // vertices (160*160)
constexpr int DD = 64;      // D
constexpr int PP = 72;      // ns: bf16 LDS row pitch
constexpr int KP = 34;      // node: halfword pitch -> dword stride 17 (2-way = free on writes)
constexpr size_t GEOM_OFF = 1u << 20;   // geometry scratch at ws+1MB, 36 dwords/(b,node)
constexpr int GREC = 36;    // geom record dwords: v[18] sv[3] cinv[6] pad mm[6] pad[2]

// scaled-NS schedule (worst-case l0 = 3e-5, u0 = 1): s_k = 2/(l_k+u_k), mu = sqrt(s)
constexpr int NS_STEPS = 11;           // step 0 is the cheap init half-step
__constant__ const float S_TAB[NS_STEPS]  = {1.999940f, 1.999730f, 1.998790f, 1.994560f,
                                             1.976020f, 1.900200f, 1.653000f, 1.241700f,
                                             1.024220f, 1.000220f, 1.000000f};
__constant__ const float MU_TAB[NS_STEPS] = {1.414192f, 1.414118f, 1.413786f, 1.412289f,
                                             1.405710f, 1.378478f, 1.285690f, 1.114316f,
                                             1.012038f, 1.000110f, 1.000000f};

typedef __attribute__((ext_vector_type(8))) short short8;
typedef __attribute__((ext_vector_type(4))) float floatx4;

__device__ __forceinline__ unsigned short f2bf(float x) {
    unsigned u = __float_as_uint(x);
    u += 0x7fffu + ((u >> 16) & 1u);        // round-to-nearest-even
    return (unsigned short)(u >> 16);
}
__device__ __forceinline__ float bf2f(unsigned short h) {
    return __uint_as_float(((unsigned)h) << 16);
}
__device__ __forceinline__ unsigned pack2bf(float a, float b) {
    return (unsigned)f2bf(a) | ((unsigned)f2bf(b) << 16);
}

// fallback-path rowptr (+ zero M/out)
__global__ void rowptr_kernel(const int* __restrict__ e0, int E, int* __restrict__ row_ptr,
                              float* __restrict__ M, float* __restrict__ out) {
    int i = blockIdx.x * blockDim.x + threadIdx.x;
    if (i < BN * 64 * 64) M[i] = 0.f;
    if (i == 0) out[0] = 0.f;
    if (i > NV) return;
    int lo = 0, hi = E;
    while (lo < hi) {
        int mid = (lo + hi) >> 1;
        if (e0[mid] < i) lo = mid + 1; else hi = mid;
    }
    row_ptr[i] = lo;
}

// Per-(batch,node) geometry + neighbor list; also zeroes M and out.
// Record: [0..17]=v[6][3], [18..20]=sv, [21..26]=cinv, [27]=pad, [28..33]=mm (int), [34..35]=pad
__global__ __launch_bounds__(256) void geom_kernel(
    const float* __restrict__ x, const int* __restrict__ e0, const int* __restrict__ e1,
    int E, float* __restrict__ geom, float* __restrict__ M, float* __restrict__ out)
{
    const int gid = blockIdx.x * 256 + threadIdx.x;
    if (gid < BN * 64 * 64) M[gid] = 0.f;
    if (gid == 0) out[0] = 0.f;
    if (gid >= BN * NV) return;
    const int b = gid / NV;
    const int n = gid - b * NV;

    // row range via binary search on sorted e0
    int lo = 0, hi = E;
    while (lo < hi) { int mid = (lo + hi) >> 1; if (e0[mid] < n) lo = mid + 1; else hi = mid; }
    const int beg = lo;
    lo = beg; hi = E;
    while (lo < hi) { int mid = (lo + hi) >> 1; if (e0[mid] < n + 1) lo = mid + 1; else hi = mid; }
    const int deg = lo - beg;

    const float* xb = x + (size_t)b * NV * 3;
    const float xn0 = xb[n * 3], xn1 = xb[n * 3 + 1], xn2 = xb[n * 3 + 2];
    float v[6][3];
    int mm[6];
    float sv0 = 0, sv1 = 0, sv2 = 0;
    float cxx = 0, cxy = 0, cxz = 0, cyy = 0, cyz = 0, czz = 0;
#pragma unroll
    for (int k = 0; k < 6; k++) {
        const int m = (k < deg) ? e1[beg + k] : n;   // m=n -> v=0 exactly
        mm[k] = m;
        const float v0 = xn0 - xb[m * 3];
        const float v1 = xn1 - xb[m * 3 + 1];
        const float v2 = xn2 - xb[m * 3 + 2];
        v[k][0] = v0; v[k][1] = v1; v[k][2] = v2;
        sv0 += v0; sv1 += v1; sv2 += v2;
        const float s2 = v0 * v0 + v1 * v1 + v2 * v2;
        cxx += s2 - v0 * v0; cyy += s2 - v1 * v1; czz += s2 - v2 * v2;
        cxy -= v0 * v1; cxz -= v0 * v2; cyz -= v1 * v2;
    }
    const float co00 = cyy * czz - cyz * cyz;
    const float co01 = cxz * cyz - cxy * czz;
    const float co02 = cxy * cyz - cxz * cyy;
    const float det  = cxx * co00 + cxy * co01 + cxz * co02;
    const float id   = 1.0f / det;
    const float i00 = co00 * id, i01 = co01 * id, i02 = co02 * id;
    const float i11 = (cxx * czz - cxz * cxz) * id;
    const float i12 = (cxz * cxy - cxx * cyz) * id;
    const float i22 = (cxx * cyy - cxy * cxy) * id;

    float4* g4 = (float4*)(geom + (size_t)gid * GREC);
    g4[0] = make_float4(v[0][0], v[0][1], v[0][2], v[1][0]);
    g4[1] = make_float4(v[1][1], v[1][2], v[2][0], v[2][1]);
    g4[2] = make_float4(v[2][2], v[3][0], v[3][1], v[3][2]);
    g4[3] = make_float4(v[4][0], v[4][1], v[4][2], v[5][0]);
    g4[4] = make_float4(v[5][1], v[5][2], sv0, sv1);
    g4[5] = make_float4(sv2, i00, i01, i02);
    g4[6] = make_float4(i11, i12, i22, 0.f);
    g4[7] = make_float4(__int_as_float(mm[0]), __int_as_float(mm[1]),
                        __int_as_float(mm[2]), __int_as_float(mm[3]));
    g4[8] = make_float4(__int_as_float(mm[4]), __int_as_float(mm[5]), 0.f, 0.f);
}

// fragment load from a [64][KP-halfword] panel (dword-aligned only)
__device__ __forceinline__ short8 ldfrag(const unsigned short* a, int row, int quad) {
    const unsigned* p = (const unsigned*)(a + row * KP + quad * 8);
    union { unsigned u[4]; short8 s; } t;
    t.u[0] = p[0]; t.u[1] = p[1]; t.u[2] = p[2]; t.u[3] = p[3];
    return t.s;
}

// FAST node kernel: geometry+neighbors from scratch record (scalar pipe),
// single-bf16 Gram panels, 4 MFMA/chunk.
__global__ __launch_bounds__(256, 4) void node_kernel_fast(
    const float* __restrict__ J, const float* __restrict__ geom,
    float* __restrict__ M)
{
    const int b    = blockIdx.y;
    const int w    = __builtin_amdgcn_readfirstlane(threadIdx.x >> 6);
    const int lane = threadIdx.x & 63;
    const int quad = lane >> 4;
    const int mrow = lane & 15;
    const int r0   = w * 16;

    __shared__ unsigned short ATh[64 * KP];
    __shared__ unsigned short BTh[64 * KP];
    for (int i = threadIdx.x; i < 64 * KP; i += 256) { ATh[i] = 0; BTh[i] = 0; }
    __syncthreads();

    const floatx4 zero4 = {0.f, 0.f, 0.f, 0.f};
    floatx4 accM[4];
#pragma unroll
    for (int c = 0; c < 4; c++) accM[c] = zero4;

    const float* Jb = J + (size_t)b * 3 * NV * DD;

    for (int chunk = blockIdx.x; chunk < NV / 4; chunk += gridDim.x) {
        const int n = chunk * 4 + w;                         // uniform
        const float* g = geom + (size_t)(b * NV + n) * GREC; // uniform -> scalar loads
        const int* gi = (const int*)(g + 28);

        const float* Jn = Jb + n * 3 * DD + lane;
        const float jn0 = Jn[0], jn1 = Jn[DD], jn2 = Jn[2 * DD];
        float jm0[6], jm1[6], jm2[6];
#pragma unroll
        for (int k = 0; k < 6; k++) {
            const float* Jm = Jb + gi[k] * 3 * DD + lane;
            jm0[k] = Jm[0]; jm1[k] = Jm[DD]; jm2[k] = Jm[2 * DD];
        }

        // lj = 2*(6*jn - sum(jm))   (padded jm = jn keeps this exact)
        const float sm0 = (jm0[0] + jm0[1]) + (jm0[2] + jm0[3]) + (jm0[4] + jm0[5]);
        const float sm1 = (jm1[0] + jm1[1]) + (jm1[2] + jm1[3]) + (jm1[4] + jm1[5]);
        const float sm2 = (jm2[0] + jm2[1]) + (jm2[2] + jm2[3]) + (jm2[4] + jm2[5]);
        const float lj0 = 12.f * jn0 - 2.f * sm0;
        const float lj1 = 12.f * jn1 - 2.f * sm1;
        const float lj2 = 12.f * jn2 - 2.f * sm2;

        // bt = sum_k v_k x jm_k - sv x jn   (padded v_k = 0)
        const float sv0 = g[18], sv1 = g[19], sv2 = g[20];
        float bt0 = sv2 * jn1 - sv1 * jn2;
        float bt1 = sv0 * jn2 - sv2 * jn0;
        float bt2 = sv1 * jn0 - sv0 * jn1;
#pragma unroll
        for (int k = 0; k < 6; k++) {
            const float v0 = g[k * 3], v1 = g[k * 3 + 1], v2 = g[k * 3 + 2];
            bt0 += v1 * jm2[k] - v2 * jm1[k];
            bt1 += v2 * jm0[k] - v0 * jm2[k];
            bt2 += v0 * jm1[k] - v1 * jm0[k];
        }

        const float i00 = g[21], i01 = g[22], i02 = g[23];
        const float i11 = g[24], i12 = g[25], i22 = g[26];
        const float cb0 = i00 * bt0 + i01 * bt1 + i02 * bt2;
        const float cb1 = i01 * bt0 + i11 * bt1 + i12 * bt2;
        const float cb2 = i02 * bt0 + i12 * bt1 + i22 * bt2;

        {
            const int base = lane * (KP / 2) + w * 3;   // dword idx; stride 17 -> 2-way free
            unsigned* A32 = (unsigned*)ATh;
            unsigned* B32 = (unsigned*)BTh;
            A32[base + 0] = pack2bf(jn0, jn1);
            A32[base + 1] = pack2bf(jn2, bt0);
            A32[base + 2] = pack2bf(bt1, bt2);
            B32[base + 0] = pack2bf(lj0, lj1);
            B32[base + 1] = pack2bf(lj2, -cb0);
            B32[base + 2] = pack2bf(-cb1, -cb2);
        }
        __syncthreads();

        const short8 ah = ldfrag(ATh, r0 + mrow, quad);
#pragma unroll
        for (int c = 0; c < 4; c++) {
            const short8 bh = ldfrag(BTh, c * 16 + mrow, quad);
            accM[c] = __builtin_amdgcn_mfma_f32_16x16x32_bf16(ah, bh, accM[c], 0, 0, 0);
        }
        __syncthreads();
    }

    float* Mb = M + b * 4096;
#pragma unroll
    for (int c = 0; c < 4; c++)
#pragma unroll
        for (int r = 0; r < 4; r++)
            atomicAdd(&Mb[(r0 + quad * 4 + r) * 64 + (c * 16 + mrow)], accM[c][r]);
}

// SLOW fallback (round-7 proven path, only if ws too small)
__global__ __launch_bounds__(256, 4) void node_kernel_slow(
    const float* __restrict__ x, const float* __restrict__ J,
    const int* __restrict__ e1, const int* __restrict__ row_ptr,
    float* __restrict__ M)
{
    const int b    = blockIdx.y;
    const int w    = __builtin_amdgcn_readfirstlane(threadIdx.x >> 6);
    const int lane = threadIdx.x & 63;
    const int quad = lane >> 4;
    const int mrow = lane & 15;
    const int r0   = w * 16;

    __shared__ unsigned short ATh[64 * KP], ATl[64 * KP];
    __shared__ unsigned short BTh[64 * KP], BTl[64 * KP];
    for (int i = threadIdx.x; i < 64 * KP; i += 256) { ATh[i]=0; ATl[i]=0; BTh[i]=0; BTl[i]=0; }
    __syncthreads();

    const floatx4 zero4 = {0.f, 0.f, 0.f, 0.f};
    floatx4 accM[4];
#pragma unroll
    for (int c = 0; c < 4; c++) accM[c] = zero4;

    const float* xb = x + (size_t)b * NV * 3;
    const float* Jb = J + (size_t)b * 3 * NV * DD;

    for (int chunk = blockIdx.x; chunk < NV / 4; chunk += gridDim.x) {
        const int n   = chunk * 4 + w;
        const int beg = row_ptr[n];
        const int deg = row_ptr[n + 1] - beg;
        int mm[6];
#pragma unroll
        for (int k = 0; k < 6; k++) {
            const int idx = beg + ((k < deg) ? k : 0);
            const int mv  = e1[idx];
            mm[k] = (k < deg) ? mv : n;
        }
        const float* Jn = Jb + n * 3 * DD + lane;
        const float jn0 = Jn[0], jn1 = Jn[DD], jn2 = Jn[2 * DD];
        float jm0[6], jm1[6], jm2[6];
#pragma unroll
        for (int k = 0; k < 6; k++) {
            const float* Jm = Jb + mm[k] * 3 * DD + lane;
            jm0[k] = Jm[0]; jm1[k] = Jm[DD]; jm2[k] = Jm[2 * DD];
        }
        const float xn0 = xb[n * 3 + 0], xn1 = xb[n * 3 + 1], xn2 = xb[n * 3 + 2];
        float va0[6], va1[6], va2[6];
#pragma unroll
        for (int k = 0; k < 6; k++) {
            va0[k] = xn0 - xb[mm[k] * 3 + 0];
            va1[k] = xn1 - xb[mm[k] * 3 + 1];
            va2[k] = xn2 - xb[mm[k] * 3 + 2];
        }
        float lj0=0, lj1=0, lj2=0, bt0=0, bt1=0, bt2=0;
        float cxx=0, cxy=0, cxz=0, cyy=0, cyz=0, czz=0;
#pragma unroll
        for (int k = 0; k < 6; k++) {
            const float v0 = va0[k], v1 = va1[k], v2 = va2[k];
            const float t0 = jm0[k]-jn0, t1 = jm1[k]-jn1, t2 = jm2[k]-jn2;
            lj0 -= t0; lj1 -= t1; lj2 -= t2;
            bt0 += v1*t2 - v2*t1; bt1 += v2*t0 - v0*t2; bt2 += v0*t1 - v1*t0;
            const float s2 = v0*v0 + v1*v1 + v2*v2;
            cxx += s2 - v0*v0; cyy += s2 - v1*v1; czz += s2 - v2*v2;
            cxy -= v0*v1; cxz -= v0*v2; cyz -= v1*v2;
        }
        lj0 *= 2.f; lj1 *= 2.f; lj2 *= 2.f;
        const float co00 = cyy*czz - cyz*cyz;
        const float co01 = cxz*cyz - cxy*czz;
        const float co02 = cxy*cyz - cxz*cyy;
        const float det  = cxx*co00 + cxy*co01 + cxz*co02;
        const float id   = 1.0f / det;
        const float i00 = co00*id, i01 = co01*id, i02 = co02*id;
        const float i11 = (cxx*czz - cxz*cxz)*id;
        const float i12 = (cxz*cxy - cxx*cyz)*id;
        const float i22 = (cxx*cyy - cxy*cxy)*id;
        const float cb0 = i00*bt0 + i01*bt1 + i02*bt2;
        const float cb1 = i01*bt0 + i11*bt1 + i12*bt2;
        const float cb2 = i02*bt0 + i12*bt1 + i22*bt2;
        {
            const int kA = w * 6;
            float av[6] = {jn0, jn1, jn2, bt0, bt1, bt2};
            float bv[6] = {lj0, lj1, lj2, -cb0, -cb1, -cb2};
#pragma unroll
            for (int i = 0; i < 6; i++) {
                unsigned short h = f2bf(av[i]);
                ATh[lane*KP + kA + i] = h; ATl[lane*KP + kA + i] = f2bf(av[i] - bf2f(h));
                h = f2bf(bv[i]);
                BTh[lane*KP + kA + i] = h; BTl[lane*KP + kA + i] = f2bf(bv[i] - bf2f(h));
            }
        }
        __syncthreads();
        const short8 ah = ldfrag(ATh, r0 + mrow, quad);
        const short8 al = ldfrag(ATl, r0 + mrow, quad);
#pragma unroll
        for (int c = 0; c < 4; c++) {
            const short8 bh = ldfrag(BTh, c*16 + mrow, quad);
            const short8 bl = ldfrag(BTl, c*16 + mrow, quad);
            accM[c] = __builtin_amdgcn_mfma_f32_16x16x32_bf16(ah, bh, accM[c], 0, 0, 0);
            accM[c] = __builtin_amdgcn_mfma_f32_16x16x32_bf16(ah, bl, accM[c], 0, 0, 0);
            accM[c] = __builtin_amdgcn_mfma_f32_16x16x32_bf16(al, bh, accM[c], 0, 0, 0);
        }
        __syncthreads();
    }
    float* Mb = M + b * 4096;
#pragma unroll
    for (int c = 0; c < 4; c++)
#pragma unroll
        for (int r = 0; r < 4; r++)
            atomicAdd(&Mb[(r0 + quad*4 + r) * 64 + (c*16 + mrow)], accM[c][r]);
}

// ---------------------------------------------------------------------------
// trace(sqrtm(M+dI)) via SCALED coupled Newton-Schulz, bf16-split MFMA.
// W_k = mu_k (1.5 I - 0.5 s_k T_k) absorbs the scaling: Y'=YW, Z'=WZ.
// Step 0: Z0=I -> T0=Y0, so W0 and Z1=W0 are elementwise; only Y1=Y0*W0 GEMMs.
// 8 waves (512 thr): wave w owns tiles (row w&3, cols (w>>2)*2 + {0,1}).
// ---------------------------------------------------------------------------
__global__ __launch_bounds__(512, 1) void ns_sqrt_kernel(const float* __restrict__ M,
                                                         float* __restrict__ out)
{
    const int b    = blockIdx.x;
    const int tid  = threadIdx.x;
    const int w    = tid >> 6;
    const int lane = tid & 63;
    const int quad = lane >> 4;
    const int mrow = lane & 15;
    const int tr   = (w & 3) * 16;        // tile-row strip
    const int tc0  = (w >> 2) * 32;       // first of two 16-col tiles

    __shared__ __align__(16) unsigned short Yh[2][64 * PP], Yl[2][64 * PP];
    __shared__ __align__(16) unsigned short Zh[2][64 * PP], Zl[2][64 * PP];
    __shared__ __align__(16) unsigned short Wh[64 * PP], Wl[64 * PP];
    __shared__ float red_s[8];
    __shared__ float tr_s;

    const float* Mb = M + b * 4096;

    // trace + Frobenius norm
    {
        float f2 = 0.f;
        for (int i = tid; i < 4096; i += 512) { const float v = Mb[i]; f2 += v * v; }
#pragma unroll
        for (int off = 32; off; off >>= 1) f2 += __shfl_down(f2, off, 64);
        if (lane == 0) red_s[w] = f2;
        if (tid < 64) {
            float d = Mb[tid * 64 + tid];
#pragma unroll
            for (int off = 32; off; off >>= 1) d += __shfl_down(d, off, 64);
            if (tid == 0) tr_s = d;
        }
    }
    __syncthreads();
    const float trM   = tr_s;
    float f2s = 0.f;
#pragma unroll
    for (int i = 0; i < 8; i++) f2s += red_s[i];
    const float fro   = sqrtf(f2s);
    const float delta = 3e-5f * trM;
    const float cnorm = fro + 2.f * delta;
    const float inv_c = 1.f / cnorm;

    // init: Y0 = (M+dI)/c; W0 = mu0(1.5I - 0.5 s0 Y0); Z1 = W0 (elementwise)
    {
        const float s0 = S_TAB[0], mu0 = MU_TAB[0];
        for (int i = tid; i < 4096; i += 512) {
            const int r = i >> 6, col = i & 63;
            float y = Mb[i] * inv_c;
            if (r == col) y += delta * inv_c;
            unsigned short h = f2bf(y);
            Yh[0][r * PP + col] = h;
            Yl[0][r * PP + col] = f2bf(y - bf2f(h));
            float wv = mu0 * (-0.5f * s0 * y);
            if (r == col) wv += mu0 * 1.5f;
            h = f2bf(wv);
            Wh[r * PP + col] = h;
            Wl[r * PP + col] = f2bf(wv - bf2f(h));
            Zh[1][r * PP + col] = h;                    // Z1 = W0
            Zl[1][r * PP + col] = Wl[r * PP + col];
        }
    }
    __syncthreads();

    const floatx4 zero4 = {0.f, 0.f, 0.f, 0.f};

    // step 0 (half): Y1 = Y0 * W0  -> buffer 1
    {
        floatx4 y0[2], y1[2], y2[2];
#pragma unroll
        for (int c = 0; c < 2; c++) { y0[c] = zero4; y1[c] = zero4; y2[c] = zero4; }
#pragma unroll
        for (int ks = 0; ks < 2; ks++) {
            const int ko = ks * 32 + quad * 8;
            const short8 yah = *(const short8*)&Yh[0][(tr + mrow) * PP + ko];
            const short8 yal = *(const short8*)&Yl[0][(tr + mrow) * PP + ko];
#pragma unroll
            for (int c = 0; c < 2; c++) {
                const short8 wbh = *(const short8*)&Wh[(tc0 + c * 16 + mrow) * PP + ko];
                const short8 wbl = *(const short8*)&Wl[(tc0 + c * 16 + mrow) * PP + ko];
                y0[c] = __builtin_amdgcn_mfma_f32_16x16x32_bf16(yah, wbh, y0[c], 0, 0, 0);
                y1[c] = __builtin_amdgcn_mfma_f32_16x16x32_bf16(yah, wbl, y1[c], 0, 0, 0);
                y2[c] = __builtin_amdgcn_mfma_f32_16x16x32_bf16(yal, wbh, y2[c], 0, 0, 0);
            }
        }
#pragma unroll
        for (int c = 0; c < 2; c++) {
#pragma unroll
            for (int r = 0; r < 4; r++) {
                const int row = tr + quad * 4 + r;
                const int col = tc0 + c * 16 + mrow;
                const float vy = y0[c][r] + y1[c][r] + y2[c][r];
                const unsigned short h = f2bf(vy);
                Yh[1][row * PP + col] = h;
                Yl[1][row * PP + col] = f2bf(vy - bf2f(h));
            }
        }
        __syncthreads();
    }

    for (int it = 1; it < NS_STEPS; ++it) {
        const int cur = it & 1, nxt = cur ^ 1;
        const float s = S_TAB[it], mu = MU_TAB[it];
        const unsigned short* yh = Yh[cur]; const unsigned short* yl = Yl[cur];
        const unsigned short* zh = Zh[cur]; const unsigned short* zl = Zl[cur];

        // ---- phase 1: T = Z*Y (2 tiles/wave) ----
        floatx4 t0[2], t1[2], t2[2];
#pragma unroll
        for (int c = 0; c < 2; c++) { t0[c] = zero4; t1[c] = zero4; t2[c] = zero4; }
#pragma unroll
        for (int ks = 0; ks < 2; ks++) {
            const int ko = ks * 32 + quad * 8;
            const short8 zah = *(const short8*)&zh[(tr + mrow) * PP + ko];
            const short8 zal = *(const short8*)&zl[(tr + mrow) * PP + ko];
#pragma unroll
            for (int c = 0; c < 2; c++) {
                const short8 ybh = *(const short8*)&yh[(tc0 + c * 16 + mrow) * PP + ko];
                const short8 ybl = *(const short8*)&yl[(tc0 + c * 16 + mrow) * PP + ko];
                t0[c] = __builtin_amdgcn_mfma_f32_16x16x32_bf16(zah, ybh, t0[c], 0, 0, 0);
                t1[c] = __builtin_amdgcn_mfma_f32_16x16x32_bf16(zah, ybl, t1[c], 0, 0, 0);
                t2[c] = __builtin_amdgcn_mfma_f32_16x16x32_bf16(zal, ybh, t2[c], 0, 0, 0);
            }
        }
        // WB W = mu*(1.5I - 0.5 s T)
#pragma unroll
        for (int c = 0; c < 2; c++) {
#pragma unroll
            for (int r = 0; r < 4; r++) {
                const int row = tr + quad * 4 + r;
                const int col = tc0 + c * 16 + mrow;
                float v = mu * (-0.5f * s) * (t0[c][r] + t1[c][r] + t2[c][r]);
                if (row == col) v += mu * 1.5f;
                const unsigned short h = f2bf(v);
                Wh[row * PP + col] = h;
                Wl[row * PP + col] = f2bf(v - bf2f(h));
            }
        }
        __syncthreads();   // sync1: W complete

        // ---- phase 2: Y' = Y*W, Z' = W*Z -> alternate buffers ----
        floatx4 y0[2], y1[2], y2[2], z0[2], z1[2], z2[2];
#pragma unroll
        for (int c = 0; c < 2; c++) {
            y0[c] = zero4; y1[c] = zero4; y2[c] = zero4;
            z0[c] = zero4; z1[c] = zero4; z2[c] = zero4;
        }
#pragma unroll
        for (int ks = 0; ks < 2; ks++) {
            const int ko = ks * 32 + quad * 8;
            const short8 yah = *(const short8*)&yh[(tr + mrow) * PP + ko];
            const short8 yal = *(const short8*)&yl[(tr + mrow) * PP + ko];
            const short8 wah = *(const short8*)&Wh[(tr + mrow) * PP + ko];
            const short8 wal = *(const short8*)&Wl[(tr + mrow) * PP + ko];
#pragma unroll
            for (int c = 0; c < 2; c++) {
                const int bc = (tc0 + c * 16 + mrow) * PP + ko;
                const short8 wbh = *(const short8*)&Wh[bc];
                const short8 wbl = *(const short8*)&Wl[bc];
                y0[c] = __builtin_amdgcn_mfma_f32_16x16x32_bf16(yah, wbh, y0[c], 0, 0, 0);
                y1[c] = __builtin_amdgcn_mfma_f32_16x16x32_bf16(yah, wbl, y1[c], 0, 0, 0);
                y2[c] = __builtin_amdgcn_mfma_f32_16x16x32_bf16(yal, wbh, y2[c], 0, 0, 0);
                const short8 zbh = *(const short8*)&zh[bc];
                const short8 zbl = *(const short8*)&zl[bc];
                z0[c] = __builtin_amdgcn_mfma_f32_16x16x32_bf16(wah, zbh, z0[c], 0, 0, 0);
                z1[c] = __builtin_amdgcn_mfma_f32_16x16x32_bf16(wah, zbl, z1[c], 0, 0, 0);
                z2[c] = __builtin_amdgcn_mfma_f32_16x16x32_bf16(wal, zbh, z2[c], 0, 0, 0);
            }
        }
#pragma unroll
        for (int c = 0; c < 2; c++) {
#pragma unroll
            for (int r = 0; r < 4; r++) {
                const int row = tr + quad * 4 + r;
                const int col = tc0 + c * 16 + mrow;
                const float vy = y0[c][r] + y1[c][r] + y2[c][r];
                const float vz = z0[c][r] + z1[c][r] + z2[c][r];
                unsigned short h = f2bf(vy);
                Yh[nxt][row * PP + col] = h;
                Yl[nxt][row * PP + col] = f2bf(vy - bf2f(h));
                h = f2bf(vz);
                Zh[nxt][row * PP + col] = h;
                Zl[nxt][row * PP + col] = f2bf(vz - bf2f(h));
            }
        }
        __syncthreads();   // sync2
    }

    const int fin = NS_STEPS & 1;   // last loop iter it=NS_STEPS-1 wrote buffer (it&1)^1
    if (tid < 64) {
        float d = bf2f(Yh[fin][tid * PP + tid]) + bf2f(Yl[fin][tid * PP + tid]);
#pragma unroll
        for (int off = 32; off; off >>= 1) d += __shfl_down(d, off, 64);
        if (tid == 0) atomicAdd(out, d * sqrtf(cnorm) * (1.0f / BN));
    }
}

extern "C" void kernel_launch(void* const* d_in, const int* in_sizes, int n_in,
                              void* d_out, int out_size, void* d_ws, size_t ws_size,
                              hipStream_t stream) {
    const float* x  = (const float*)d_in[0];
    const float* J  = (const float*)d_in[1];
    const int*   e0 = (const int*)d_in[2];
    const int*   e1 = (const int*)d_in[3];
    const int E = in_sizes[2];

    int*   row_ptr = (int*)d_ws;
    float* M       = (float*)((char*)d_ws + 128 * 1024);
    float* geom    = (float*)((char*)d_ws + GEOM_OFF);
    const size_t need = GEOM_OFF + (size_t)BN * NV * GREC * sizeof(float);

    if (ws_size >= need) {
        geom_kernel<<<(BN * NV + 255) / 256, 256, 0, stream>>>(x, e0, e1, E, geom, M, (float*)d_out);
        node_kernel_fast<<<dim3(512, BN), 256, 0, stream>>>(J, geom, M);
    } else {
        rowptr_kernel<<<(NV + 1 + 255) / 256, 256, 0, stream>>>(e0, E, row_ptr, M, (float*)d_out);
        node_kernel_slow<<<dim3(512, BN), 256, 0, stream>>>(x, J, e1, row_ptr, M);
    }
    ns_sqrt_kernel<<<BN, 512, 0, stream>>>(M, (float*)d_out);
}